// Round 1
// baseline (1005.234 us; speedup 1.0000x reference)
//
#include <hip/hip_runtime.h>
#include <cstdint>
#include <cstddef>

// ---------------------------------------------------------------------------
// EncoderBlock: S=4096, E=2048, H=8192, fp32 in/out, bf16 MFMA internally.
// R5: port all six GEMMs to the 8-phase-template schedule (T3+T4+T5) at
//   BM=128 x BN=256, BK=64, 8 waves (512 thr), per-wave 64x64 output.
//   - 4 phases per K-tile (template cadence: 8 phases / 2 K-tiles), each
//     {ds_read subtile ; stage-issue ; s_barrier ; lgkmcnt(0) ; setprio(1)
//      8x MFMA ; setprio(0) ; s_barrier}.
//   - counted vmcnt(2) once per K-tile (never 0 in main loop): next tile's
//     A-loads stay in flight across the gate.
//   - staging for tile t+1: A issued at t-1.q3 (its buffer's last read is
//     in q2 -> overwrite after q2's trailing barrier is race-free),
//     B01 at t.q0, B23 at t.q1.
//   - XOR bank-swizzle on global source + swizzled ds_read (unchanged,
//     verified: SQ_LDS_BANK_CONFLICT == 0).
//   Epilogues identical to R4. LDS 96 KB double-buffered, 1 block/CU.
// ---------------------------------------------------------------------------

constexpr int S = 4096;
constexpr int E = 2048;
constexpr int H = 8192;

typedef __bf16 bf16;
typedef bf16  bf16x8 __attribute__((ext_vector_type(8)));
typedef bf16  bf16x4 __attribute__((ext_vector_type(4)));
typedef float f32x4  __attribute__((ext_vector_type(4)));

typedef __attribute__((address_space(1))) void as1_void;
typedef __attribute__((address_space(3))) void as3_void;

__device__ __forceinline__ void ldg2lds16(const void* g, void* l) {
  __builtin_amdgcn_global_load_lds((as1_void*)g, (as3_void*)l, 16, 0, 0);
}

// ---------------------------------------------------------------------------
// GEMM: C[M,N] = A[M,K] @ Bt[N,K]^T. Tile 128x256, K-step 64. Epilogues:
// EPI 0: out bf16 = acc + bias[col]                   (Q,K proj)
// EPI 1: out bf16 = acc + bias[row]                   (V^T proj)
// EPI 2: out bf16 = acc * scale                       (scores)
// EPI 3: out f32  = acc + add (f32), fused LN sums    (attn residual)
// EPI 4: out bf16 = relu(acc + bias[col])             (FFN act)
// EPI 5: out f32  = acc + bias[col] + addb (bf16), fused LN sums (FFN resid)
// Requires M%128==0, N%256==0, K%64==0, (#workgroups)%8==0, K/64 >= 4.
// ---------------------------------------------------------------------------
template <int EPI>
__global__ __launch_bounds__(512, 2)
void gemm8(const bf16* __restrict__ A, int lda,
           const bf16* __restrict__ Bt, int ldb,
           bf16* __restrict__ Cb, float* __restrict__ Cf, int ldc,
           const float* __restrict__ bias, const float* __restrict__ add,
           const bf16* __restrict__ addb,
           float* __restrict__ red, int M, int N, int K, float scale)
{
  __shared__ bf16 sA[2][128 * 64];   // 32 KB (double-buffered A tile)
  __shared__ bf16 sB[2][256 * 64];   // 64 KB (double-buffered B tile)

  const int tid  = threadIdx.x;
  const int lane = tid & 63;
  const int wave = tid >> 6;

  // XCD-chunked block swizzle: HW block i -> XCD i%8; give each XCD a
  // contiguous logical chunk so neighboring tiles share the A panel in L2.
  const int nbx = gridDim.x;
  const int nwg = nbx * gridDim.y;
  const int bid = blockIdx.y * nbx + blockIdx.x;
  const int wg  = (bid & 7) * (nwg >> 3) + (bid >> 3);
  const int m0  = (wg / nbx) * 128;
  const int n0  = (wg % nbx) * 256;

  // 8 waves: 2 (M) x 4 (N); each wave owns a 64x64 output sub-tile.
  const int wm = (wave & 1) * 64;
  const int wn = (wave >> 1) * 64;

  // --- staging: thread t covers row t>>3 (0..63), 16B chunk t&7, per call.
  // Global chunk index XOR-swizzled by (row&7): LDS row r slot s holds
  // global chunk s^(r&7).
  const int tr  = tid >> 3;
  const int tc  = tid & 7;
  const int gsw = (tc ^ (tr & 7)) * 8;
  const bf16* gA = A  + (size_t)(m0 + tr) * lda + gsw;
  const bf16* gB = Bt + (size_t)(n0 + tr) * ldb + gsw;
  const size_t a64 = (size_t)64 * lda;
  const size_t b64 = (size_t)64 * ldb;

  // --- MFMA fragment addressing (reader side of the swizzle) ---
  const int fr = lane & 15;
  const int fq = lane >> 4;
  const int p0 = (fq ^ (fr & 7)) * 8;   // kk=0 slot offset (elems)
  const int p1 = p0 ^ 32;               // kk=1

  const int NT = K >> 6;

  // --- prologue: stage tile0 (A+B) and tile1's A; gate leaves tile1-A live
  ldg2lds16(gA,             &sA[0][tid * 8]);
  ldg2lds16(gA + a64,       &sA[0][4096  + tid * 8]);
  ldg2lds16(gB,             &sB[0][tid * 8]);
  ldg2lds16(gB + b64,       &sB[0][4096  + tid * 8]);
  ldg2lds16(gB + 2 * b64,   &sB[0][8192  + tid * 8]);
  ldg2lds16(gB + 3 * b64,   &sB[0][12288 + tid * 8]);
  ldg2lds16(gA + 64,        &sA[1][tid * 8]);
  ldg2lds16(gA + 64 + a64,  &sA[1][4096  + tid * 8]);
  asm volatile("s_waitcnt vmcnt(2)" ::: "memory");
  __builtin_amdgcn_s_barrier();

  f32x4 acc[4][4] = {};

  for (int t = 0; t < NT; ++t) {
    const int bu = t & 1, nx = bu ^ 1;
    const bf16* rA = &sA[bu][(wm + fr) * 64];
    const bf16* rB = &sB[bu][(wn + fr) * 64];
    bf16x8 aF0[2], aF1[2], bF0[4], bF1[4];

    // ---- phase 0: read A-lo + B-lo; stage B01(t+1) ----
    aF0[0] = *(const bf16x8*)(rA + p0);
    aF1[0] = *(const bf16x8*)(rA + p1);
    aF0[1] = *(const bf16x8*)(rA + 1024 + p0);
    aF1[1] = *(const bf16x8*)(rA + 1024 + p1);
    bF0[0] = *(const bf16x8*)(rB + p0);
    bF1[0] = *(const bf16x8*)(rB + p1);
    bF0[1] = *(const bf16x8*)(rB + 1024 + p0);
    bF1[1] = *(const bf16x8*)(rB + 1024 + p1);
    if (t + 1 < NT) {
      const bf16* g = gB + ((size_t)(t + 1) << 6);
      ldg2lds16(g,       &sB[nx][tid * 8]);
      ldg2lds16(g + b64, &sB[nx][4096 + tid * 8]);
    }
    __builtin_amdgcn_s_barrier();
    asm volatile("s_waitcnt lgkmcnt(0)" ::: "memory");
    __builtin_amdgcn_s_setprio(1);
#pragma unroll
    for (int i = 0; i < 2; ++i)
#pragma unroll
      for (int j = 0; j < 2; ++j) {
        acc[i][j] = __builtin_amdgcn_mfma_f32_16x16x32_bf16(aF0[i], bF0[j], acc[i][j], 0, 0, 0);
        acc[i][j] = __builtin_amdgcn_mfma_f32_16x16x32_bf16(aF1[i], bF1[j], acc[i][j], 0, 0, 0);
      }
    __builtin_amdgcn_s_setprio(0);
    __builtin_amdgcn_s_barrier();

    // ---- phase 1: read B-hi; stage B23(t+1) ----
    bF0[2] = *(const bf16x8*)(rB + 2048 + p0);
    bF1[2] = *(const bf16x8*)(rB + 2048 + p1);
    bF0[3] = *(const bf16x8*)(rB + 3072 + p0);
    bF1[3] = *(const bf16x8*)(rB + 3072 + p1);
    if (t + 1 < NT) {
      const bf16* g = gB + ((size_t)(t + 1) << 6) + 2 * b64;
      ldg2lds16(g,       &sB[nx][8192  + tid * 8]);
      ldg2lds16(g + b64, &sB[nx][12288 + tid * 8]);
    }
    __builtin_amdgcn_s_barrier();
    asm volatile("s_waitcnt lgkmcnt(0)" ::: "memory");
    __builtin_amdgcn_s_setprio(1);
#pragma unroll
    for (int i = 0; i < 2; ++i)
#pragma unroll
      for (int j = 0; j < 2; ++j) {
        acc[i][2 + j] = __builtin_amdgcn_mfma_f32_16x16x32_bf16(aF0[i], bF0[2 + j], acc[i][2 + j], 0, 0, 0);
        acc[i][2 + j] = __builtin_amdgcn_mfma_f32_16x16x32_bf16(aF1[i], bF1[2 + j], acc[i][2 + j], 0, 0, 0);
      }
    __builtin_amdgcn_s_setprio(0);
    __builtin_amdgcn_s_barrier();

    // ---- phase 2: read A-hi (last read of this buffer) ----
    aF0[0] = *(const bf16x8*)(rA + 2048 + p0);
    aF1[0] = *(const bf16x8*)(rA + 2048 + p1);
    aF0[1] = *(const bf16x8*)(rA + 3072 + p0);
    aF1[1] = *(const bf16x8*)(rA + 3072 + p1);
    __builtin_amdgcn_s_barrier();
    asm volatile("s_waitcnt lgkmcnt(0)" ::: "memory");
    __builtin_amdgcn_s_setprio(1);
#pragma unroll
    for (int i = 0; i < 2; ++i)
#pragma unroll
      for (int j = 0; j < 2; ++j) {
        acc[2 + i][j] = __builtin_amdgcn_mfma_f32_16x16x32_bf16(aF0[i], bF0[j], acc[2 + i][j], 0, 0, 0);
        acc[2 + i][j] = __builtin_amdgcn_mfma_f32_16x16x32_bf16(aF1[i], bF1[j], acc[2 + i][j], 0, 0, 0);
      }
    __builtin_amdgcn_s_setprio(0);
    __builtin_amdgcn_s_barrier();

    // ---- phase 3: stage A(t+2) into CURRENT buffer (all A reads of it
    // finished at phase 2's trailing barrier); MFMA hi x hi; counted gate.
    if (t + 2 < NT) {
      const bf16* g = gA + ((size_t)(t + 2) << 6);
      ldg2lds16(g,       &sA[bu][tid * 8]);
      ldg2lds16(g + a64, &sA[bu][4096 + tid * 8]);
    }
    __builtin_amdgcn_s_barrier();
    __builtin_amdgcn_s_setprio(1);
#pragma unroll
    for (int i = 0; i < 2; ++i)
#pragma unroll
      for (int j = 0; j < 2; ++j) {
        acc[2 + i][2 + j] = __builtin_amdgcn_mfma_f32_16x16x32_bf16(aF0[i], bF0[2 + j], acc[2 + i][2 + j], 0, 0, 0);
        acc[2 + i][2 + j] = __builtin_amdgcn_mfma_f32_16x16x32_bf16(aF1[i], bF1[2 + j], acc[2 + i][2 + j], 0, 0, 0);
      }
    __builtin_amdgcn_s_setprio(0);
    // gate: tile t+1's 6 loads (A @ t-1.q3, B01 @ q0, B23 @ q1) must be
    // done; the 2 newest (A of t+2, issued this phase) may stay in flight.
    if (t + 2 < NT) {
      asm volatile("s_waitcnt vmcnt(2)" ::: "memory");
    } else {
      asm volatile("s_waitcnt vmcnt(0)" ::: "memory");
    }
    __builtin_amdgcn_s_barrier();
  }

  // epilogue: C/D layout (16x16x32): row = (lane>>4)*4 + reg, col = lane&15
  const int er = m0 + wm + fq * 4;
  const int ec = n0 + wn + fr;
  float ls = 0.f, ls2 = 0.f;
#pragma unroll
  for (int i = 0; i < 4; ++i) {
#pragma unroll
    for (int r = 0; r < 4; ++r) {
      const int gr = er + i * 16 + r;
#pragma unroll
      for (int j = 0; j < 4; ++j) {
        const int gc = ec + j * 16;
        const size_t idx = (size_t)gr * ldc + gc;
        float v = acc[i][j][r];
        if (EPI == 0) {
          v += bias[gc];
          Cb[idx] = (bf16)v;
        } else if (EPI == 1) {
          v += bias[gr];
          Cb[idx] = (bf16)v;
        } else if (EPI == 2) {
          Cb[idx] = (bf16)(v * scale);
        } else if (EPI == 3) {
          v += add[idx];
          Cf[idx] = v; ls += v; ls2 += v * v;
        } else if (EPI == 4) {
          v += bias[gc];
          v = v > 0.f ? v : 0.f;
          Cb[idx] = (bf16)v;
        } else {  // EPI == 5
          v += bias[gc] + (float)addb[idx];
          Cf[idx] = v; ls += v; ls2 += v * v;
        }
      }
    }
  }

  if (EPI == 3 || EPI == 5) {
#pragma unroll
    for (int o = 32; o; o >>= 1) {
      ls  += __shfl_xor(ls,  o, 64);
      ls2 += __shfl_xor(ls2, o, 64);
    }
    float* sred = (float*)sA;   // safe: all LDS traffic done (final barrier)
    if (lane == 0) { sred[wave * 2] = ls; sred[wave * 2 + 1] = ls2; }
    __syncthreads();
    if (tid == 0) {
      float a = 0.f, b = 0.f;
#pragma unroll
      for (int w = 0; w < 8; ++w) { a += sred[w * 2]; b += sred[w * 2 + 1]; }
      atomicAdd(red,     a);
      atomicAdd(red + 1, b);
    }
  }
}

// ---------------------------------------------------------------------------
__global__ __launch_bounds__(256)
void cvt_f32_bf16(const float* __restrict__ src, bf16* __restrict__ dst)
{
  const size_t i = ((size_t)blockIdx.x * 256 + threadIdx.x) * 4;
  const float4 t = *(const float4*)(src + i);
  bf16x4 b;
  b[0] = (bf16)t.x; b[1] = (bf16)t.y; b[2] = (bf16)t.z; b[3] = (bf16)t.w;
  *(bf16x4*)(dst + i) = b;
}

// fp32 [R,C] -> bf16 [C,R]
__global__ __launch_bounds__(256)
void transpose_cvt(const float* __restrict__ src, bf16* __restrict__ dst, int R, int C)
{
  __shared__ float tile[32][33];
  const int c0 = blockIdx.x * 32, r0 = blockIdx.y * 32;
  const int tx = threadIdx.x & 31, ty = threadIdx.x >> 5;
#pragma unroll
  for (int rr = ty; rr < 32; rr += 8)
    tile[rr][tx] = src[(size_t)(r0 + rr) * C + (c0 + tx)];
  __syncthreads();
#pragma unroll
  for (int rr = ty; rr < 32; rr += 8)
    dst[(size_t)(c0 + rr) * R + (r0 + tx)] = (bf16)tile[tx][rr];
}

// ---------------------------------------------------------------------------
__global__ __launch_bounds__(256)
void softmax_rows(bf16* __restrict__ P)
{
  const int row  = blockIdx.x;
  bf16* p = P + (size_t)row * 4096;
  const int tid  = threadIdx.x;
  const int lane = tid & 63, wave = tid >> 6;

  bf16x8 c0 = *(const bf16x8*)(p + tid * 16);
  bf16x8 c1 = *(const bf16x8*)(p + tid * 16 + 8);
  float v[16];
#pragma unroll
  for (int i = 0; i < 8; ++i) { v[i] = (float)c0[i]; v[8 + i] = (float)c1[i]; }

  float m = v[0];
#pragma unroll
  for (int i = 1; i < 16; ++i) m = fmaxf(m, v[i]);
#pragma unroll
  for (int o = 32; o; o >>= 1) m = fmaxf(m, __shfl_xor(m, o, 64));
  __shared__ float sred[8];
  if (lane == 0) sred[wave] = m;
  __syncthreads();
  m = fmaxf(fmaxf(sred[0], sred[1]), fmaxf(sred[2], sred[3]));

  float s = 0.f;
#pragma unroll
  for (int i = 0; i < 16; ++i) { v[i] = __expf(v[i] - m); s += v[i]; }
#pragma unroll
  for (int o = 32; o; o >>= 1) s += __shfl_xor(s, o, 64);
  if (lane == 0) sred[4 + wave] = s;
  __syncthreads();
  s = sred[4] + sred[5] + sred[6] + sred[7];

  const float inv = 1.f / s;
  bf16x8 o0, o1;
#pragma unroll
  for (int i = 0; i < 8; ++i) { o0[i] = (bf16)(v[i] * inv); o1[i] = (bf16)(v[8 + i] * inv); }
  *(bf16x8*)(p + tid * 16)     = o0;
  *(bf16x8*)(p + tid * 16 + 8) = o1;
}

// ---------------------------------------------------------------------------
__global__ void ln_finalize(float* red, float n)
{
  const float mu  = red[0] / n;
  const float var = red[1] / n - mu * mu;
  red[2] = mu;
  red[3] = rsqrtf(var + 1e-5f);
}

// of and ob each nullable
__global__ __launch_bounds__(256)
void ln_apply(const float* __restrict__ y, const float* __restrict__ red,
              float* __restrict__ of, bf16* __restrict__ ob)
{
  const float mu = red[2], rs = red[3];
  const size_t i = ((size_t)blockIdx.x * 256 + threadIdx.x) * 4;
  float4 t = *(const float4*)(y + i);
  t.x = (t.x - mu) * rs; t.y = (t.y - mu) * rs;
  t.z = (t.z - mu) * rs; t.w = (t.w - mu) * rs;
  if (of) *(float4*)(of + i) = t;
  if (ob) {
    bf16x4 b;
    b[0] = (bf16)t.x; b[1] = (bf16)t.y; b[2] = (bf16)t.z; b[3] = (bf16)t.w;
    *(bf16x4*)(ob + i) = b;
  }
}

// ---------------------------------------------------------------------------
extern "C" void kernel_launch(void* const* d_in, const int* in_sizes, int n_in,
                              void* d_out, int out_size, void* d_ws, size_t ws_size,
                              hipStream_t stream)
{
  const float* x  = (const float*)d_in[0];
  const float* Wq = (const float*)d_in[1];
  const float* bq = (const float*)d_in[2];
  const float* Wk = (const float*)d_in[3];
  const float* bk = (const float*)d_in[4];
  const float* Wv = (const float*)d_in[5];
  const float* bv = (const float*)d_in[6];
  const float* W1 = (const float*)d_in[7];
  const float* b1 = (const float*)d_in[8];
  const float* W2 = (const float*)d_in[9];
  const float* b2 = (const float*)d_in[10];
  float* out = (float*)d_out;

  const size_t MB = 1ull << 20;
  char* ws = (char*)d_ws;

  // Layout, 216 MB peak:
  //   0- 16: xb (x bf16); after LN1, hb (h bf16) in place
  //  16- 24: WqT   24- 32: WkT   32- 40: WvT
  //  40- 72: W1T   72-104: W2T
  // 104-168: Qb(104-120) | Kb(120-136) | Pb(136-168); reused as act(104-168)
  // 168-184: VbT
  // 184-216: y (fp32; attn out, then FFN2 out)
  // 216+   : red (8 floats)
  bf16*  xb  = (bf16*)(ws);
  bf16*  hb  = xb;
  bf16*  WqT = (bf16*)(ws + 16 * MB);
  bf16*  WkT = (bf16*)(ws + 24 * MB);
  bf16*  WvT = (bf16*)(ws + 32 * MB);
  bf16*  W1T = (bf16*)(ws + 40 * MB);
  bf16*  W2T = (bf16*)(ws + 72 * MB);
  bf16*  Qb  = (bf16*)(ws + 104 * MB);
  bf16*  Kb  = (bf16*)(ws + 120 * MB);
  bf16*  Pb  = (bf16*)(ws + 136 * MB);
  bf16*  act = (bf16*)(ws + 104 * MB);
  bf16*  VbT = (bf16*)(ws + 168 * MB);
  float* y   = (float*)(ws + 184 * MB);
  float* red = (float*)(ws + 216 * MB);

  hipMemsetAsync(red, 0, 32, stream);

  const dim3 blk(256);
  const dim3 blkg(512);
  const int nElemBlocks = (S * E) / 1024;

  cvt_f32_bf16<<<dim3(nElemBlocks), blk, 0, stream>>>(x, xb);
  transpose_cvt<<<dim3(E / 32, E / 32), blk, 0, stream>>>(Wq, WqT, E, E);
  transpose_cvt<<<dim3(E / 32, E / 32), blk, 0, stream>>>(Wk, WkT, E, E);
  transpose_cvt<<<dim3(E / 32, E / 32), blk, 0, stream>>>(Wv, WvT, E, E);
  transpose_cvt<<<dim3(H / 32, E / 32), blk, 0, stream>>>(W1, W1T, E, H);
  transpose_cvt<<<dim3(E / 32, H / 32), blk, 0, stream>>>(W2, W2T, H, E);

  // Q = x@Wq + bq, K = x@Wk + bk (bf16 out)
  gemm8<0><<<dim3(E / 256, S / 128), blkg, 0, stream>>>(
      xb, E, WqT, E, Qb, nullptr, E, bq, nullptr, nullptr, nullptr, S, E, E, 0.f);
  gemm8<0><<<dim3(E / 256, S / 128), blkg, 0, stream>>>(
      xb, E, WkT, E, Kb, nullptr, E, bk, nullptr, nullptr, nullptr, S, E, E, 0.f);
  // V^T[E,S] = WvT @ x^T + bv[row]
  gemm8<1><<<dim3(S / 256, E / 128), blkg, 0, stream>>>(
      WvT, E, xb, E, VbT, nullptr, S, bv, nullptr, nullptr, nullptr, E, S, E, 0.f);

  // scores = (Q @ K^T)/64 -> bf16, softmax rows
  gemm8<2><<<dim3(S / 256, S / 128), blkg, 0, stream>>>(
      Qb, E, Kb, E, Pb, nullptr, S, nullptr, nullptr, nullptr, nullptr, S, S, E, 1.0f / 64.0f);
  softmax_rows<<<dim3(S), blk, 0, stream>>>(Pb);

  // y = x + P @ V (fp32, fused LN1 sums)
  gemm8<3><<<dim3(E / 256, S / 128), blkg, 0, stream>>>(
      Pb, S, VbT, S, nullptr, y, E, nullptr, x, nullptr, red, S, E, S, 0.f);
  ln_finalize<<<1, 1, 0, stream>>>(red, (float)((size_t)S * E));
  ln_apply<<<dim3(nElemBlocks), blk, 0, stream>>>(y, red, nullptr, hb);

  // act = relu(h @ W1 + b1) -> bf16
  gemm8<4><<<dim3(H / 256, S / 128), blkg, 0, stream>>>(
      hb, E, W1T, E, act, nullptr, H, b1, nullptr, nullptr, nullptr, S, H, E, 0.f);

  // y = h + act @ W2 + b2 (fp32, fused LN2 sums)
  gemm8<5><<<dim3(E / 256, S / 128), blkg, 0, stream>>>(
      act, H, W2T, H, nullptr, y, E, b2, nullptr, hb, red + 4, S, E, H, 0.f);
  ln_finalize<<<1, 1, 0, stream>>>(red + 4, (float)((size_t)S * E));
  ln_apply<<<dim3(nElemBlocks), blk, 0, stream>>>(y, red + 4, out, nullptr);
}

// Round 3
// 957.413 us; speedup vs baseline: 1.0499x; 1.0499x over previous
//
#include <hip/hip_runtime.h>
#include <cstdint>
#include <cstddef>

// ---------------------------------------------------------------------------
// EncoderBlock: S=4096, E=2048, H=8192, fp32 in/out, bf16 MFMA internally.
// R6 (resubmit; R2 bench was an infra GPUAcquisitionTimeout, kernel never ran):
// the 256^2 8-phase template at its PROVEN geometry (m201-class):
//   BM=BN=256, BK=64, 8 waves (2Mx4N), per-wave 128x64, 16 MFMA/phase,
//   quadrant zigzag (0,0)->(0,1)->(1,1)->(1,0) with operand register reuse,
//   one 64-row half-tile staged per phase (2 x global_load_lds), counted
//   vmcnt(6) gate once per K-tile (never 0 in steady state).
//   Region-retire analysis (all at phase-end barriers):
//     A rows g0/g2 retire ph0; B rows (all) retire ph1; A rows g1/g3 ph2.
//   Staging schedule for tile u=t+1 (buf = buf(t-1)) / u=t+2 (buf = buf(t)):
//     t-1.ph1: A-g0,g2(t+1)   t-1.ph2: B-g0,g1(t+1)  t-1.ph3: B-g2,g3(t+1)
//     t.ph0:   A-g1,g3(t+1)   t.ph1:   A-g0,g2(t+2)  t.ph2:  B-g0,g1(t+2)
//     t.ph3:   B-g2,g3(t+2)   gate vmcnt(6) at end of t.ph3.
// Launch-graph restructuring so 256^2 tiles fill the chip:
//   - Q,K projections merged into one [S,4096] GEMM (256 WGs).
//   - PV and FFN2 (N=2048 -> 128 tiles) split-K x2 -> 256 WGs, raw fp32
//     partials + fused combine(+residual/bias)+LN-sums kernel.
//   - scores 256 WGs, FFN1 512 WGs, V^T stays 128 WGs (34 GF only).
// ---------------------------------------------------------------------------

constexpr int S = 4096;
constexpr int E = 2048;
constexpr int H = 8192;

typedef __bf16 bf16;
typedef bf16  bf16x8 __attribute__((ext_vector_type(8)));
typedef bf16  bf16x4 __attribute__((ext_vector_type(4)));
typedef float f32x4  __attribute__((ext_vector_type(4)));

typedef __attribute__((address_space(1))) void as1_void;
typedef __attribute__((address_space(3))) void as3_void;

__device__ __forceinline__ void ldg2lds16(const void* g, void* l) {
  __builtin_amdgcn_global_load_lds((as1_void*)g, (as3_void*)l, 16, 0, 0);
}

// ---------------------------------------------------------------------------
// gemm256: C[M,N] = A[M,K] @ Bt[N,K]^T. Tile 256x256, BK=64. Epilogues:
// EPI 0: out bf16 = acc + bias[col]        (merged QK proj)
// EPI 1: out bf16 = acc + bias[row]        (V^T proj)
// EPI 2: out bf16 = acc * scale            (scores)
// EPI 4: out bf16 = relu(acc + bias[col])  (FFN act)
// EPI 6: out f32  = acc (raw partial; dst = kh ? Cf2 : Cf)   (split-K)
// Requires M%256==0, N%256==0, Keff%64==0, Keff/64 >= 2, nwg%8==0.
// ---------------------------------------------------------------------------
template <int EPI, bool SPLITK>
__global__ __launch_bounds__(512, 2)
void gemm256(const bf16* __restrict__ A, int lda,
             const bf16* __restrict__ Bt, int ldb,
             bf16* __restrict__ Cb, float* __restrict__ Cf,
             float* __restrict__ Cf2, int ldc,
             const float* __restrict__ bias,
             int M, int N, int K, float scale)
{
  __shared__ bf16 sA[2][256 * 64];   // 64 KB
  __shared__ bf16 sB[2][256 * 64];   // 64 KB

  const int tid  = threadIdx.x;
  const int lane = tid & 63;
  const int wave = tid >> 6;

  // XCD-chunked swizzle (nwg % 8 == 0 -> bijective)
  const int nbx = gridDim.x;
  const int nwg = nbx * gridDim.y;
  const int bid = blockIdx.y * nbx + blockIdx.x;
  int wg = (bid & 7) * (nwg >> 3) + (bid >> 3);

  int kh = 0;
  if (SPLITK) { const int hw = nwg >> 1; if (wg >= hw) { kh = 1; wg -= hw; } }
  const int ntx  = N >> 8;
  const int m0   = (wg / ntx) * 256;
  const int n0   = (wg % ntx) * 256;
  const int Keff = SPLITK ? (K >> 1) : K;
  if (SPLITK) { const size_t ko = (size_t)kh * Keff; A += ko; Bt += ko; }

  // staging: thread covers row tr (0..63) of a 64-row group, 16B chunk tc.
  // Global chunk XOR-swizzled by (row&7); LDS stays linear (gload_lds rule).
  const int tr  = tid >> 3;
  const int tc  = tid & 7;
  const int gsw = (tc ^ (tr & 7)) * 8;
  const bf16* gA = A  + (size_t)(m0 + tr) * lda + gsw;
  const bf16* gB = Bt + (size_t)(n0 + tr) * ldb + gsw;
  const size_t a64 = (size_t)64 * lda;
  const size_t b64 = (size_t)64 * ldb;

#define STAGE_A(t, g, b) ldg2lds16(gA + ((size_t)(t) << 6) + (size_t)(g) * a64, \
                                   &sA[b][(g) * 4096 + tid * 8])
#define STAGE_B(t, g, b) ldg2lds16(gB + ((size_t)(t) << 6) + (size_t)(g) * b64, \
                                   &sB[b][(g) * 4096 + tid * 8])

  // reader side of the swizzle
  const int fr = lane & 15;
  const int fq = lane >> 4;
  const int p0 = (fq ^ (fr & 7)) * 8;
  const int p1 = p0 ^ 32;
  const int wm = (wave & 1) * 128;   // per-wave rows: wm..wm+127
  const int wn = (wave >> 1) * 64;   // per-wave cols: wn..wn+63

  const int NT = Keff >> 6;

  // --- prologue: tile0 full (8 loads oldest), tile1 partial (6 loads) ---
  STAGE_A(0, 0, 0); STAGE_A(0, 1, 0); STAGE_A(0, 2, 0); STAGE_A(0, 3, 0);
  STAGE_B(0, 0, 0); STAGE_B(0, 1, 0); STAGE_B(0, 2, 0); STAGE_B(0, 3, 0);
  if (NT > 1) {
    STAGE_A(1, 0, 1); STAGE_A(1, 2, 1);
    STAGE_B(1, 0, 1); STAGE_B(1, 1, 1); STAGE_B(1, 2, 1); STAGE_B(1, 3, 1);
    asm volatile("s_waitcnt vmcnt(6)" ::: "memory");
  } else {
    asm volatile("s_waitcnt vmcnt(0)" ::: "memory");
  }
  __builtin_amdgcn_s_barrier();

  f32x4 acc[8][4] = {};

  for (int t = 0; t < NT; ++t) {
    const int bu = t & 1, nx = bu ^ 1;
    const bf16* rA = &sA[bu][(wm + fr) * 64];
    const bf16* rB = &sB[bu][(wn + fr) * 64];
    bf16x8 a0[4], a1[4], bl0[2], bl1[2], bh0[2], bh1[2];

    // ---- phase 0: read A-lo(8) + B-lo(4); stage A-g1,g3(t+1)->nx ----
#pragma unroll
    for (int i = 0; i < 4; ++i) {
      a0[i] = *(const bf16x8*)(rA + i * 1024 + p0);
      a1[i] = *(const bf16x8*)(rA + i * 1024 + p1);
    }
#pragma unroll
    for (int j = 0; j < 2; ++j) {
      bl0[j] = *(const bf16x8*)(rB + j * 1024 + p0);
      bl1[j] = *(const bf16x8*)(rB + j * 1024 + p1);
    }
    if (t + 1 < NT) { STAGE_A(t + 1, 1, nx); STAGE_A(t + 1, 3, nx); }
    __builtin_amdgcn_s_barrier();
    asm volatile("s_waitcnt lgkmcnt(0)" ::: "memory");
    __builtin_amdgcn_s_setprio(1);
#pragma unroll
    for (int i = 0; i < 4; ++i)
#pragma unroll
      for (int j = 0; j < 2; ++j) {
        acc[i][j] = __builtin_amdgcn_mfma_f32_16x16x32_bf16(a0[i], bl0[j], acc[i][j], 0, 0, 0);
        acc[i][j] = __builtin_amdgcn_mfma_f32_16x16x32_bf16(a1[i], bl1[j], acc[i][j], 0, 0, 0);
      }
    __builtin_amdgcn_s_setprio(0);
    __builtin_amdgcn_s_barrier();

    // ---- phase 1: read B-hi(4); stage A-g0,g2(t+2)->bu (retired ph0) ----
#pragma unroll
    for (int j = 0; j < 2; ++j) {
      bh0[j] = *(const bf16x8*)(rB + (2 + j) * 1024 + p0);
      bh1[j] = *(const bf16x8*)(rB + (2 + j) * 1024 + p1);
    }
    if (t + 2 < NT) { STAGE_A(t + 2, 0, bu); STAGE_A(t + 2, 2, bu); }
    __builtin_amdgcn_s_barrier();
    asm volatile("s_waitcnt lgkmcnt(0)" ::: "memory");
    __builtin_amdgcn_s_setprio(1);
#pragma unroll
    for (int i = 0; i < 4; ++i)
#pragma unroll
      for (int j = 0; j < 2; ++j) {
        acc[i][2 + j] = __builtin_amdgcn_mfma_f32_16x16x32_bf16(a0[i], bh0[j], acc[i][2 + j], 0, 0, 0);
        acc[i][2 + j] = __builtin_amdgcn_mfma_f32_16x16x32_bf16(a1[i], bh1[j], acc[i][2 + j], 0, 0, 0);
      }
    __builtin_amdgcn_s_setprio(0);
    __builtin_amdgcn_s_barrier();

    // ---- phase 2: read A-hi(8, reuse a regs); stage B-g0,g1(t+2)->bu ----
#pragma unroll
    for (int i = 0; i < 4; ++i) {
      a0[i] = *(const bf16x8*)(rA + 4096 + i * 1024 + p0);
      a1[i] = *(const bf16x8*)(rA + 4096 + i * 1024 + p1);
    }
    if (t + 2 < NT) { STAGE_B(t + 2, 0, bu); STAGE_B(t + 2, 1, bu); }
    __builtin_amdgcn_s_barrier();
    asm volatile("s_waitcnt lgkmcnt(0)" ::: "memory");
    __builtin_amdgcn_s_setprio(1);
#pragma unroll
    for (int i = 0; i < 4; ++i)
#pragma unroll
      for (int j = 0; j < 2; ++j) {
        acc[4 + i][2 + j] = __builtin_amdgcn_mfma_f32_16x16x32_bf16(a0[i], bh0[j], acc[4 + i][2 + j], 0, 0, 0);
        acc[4 + i][2 + j] = __builtin_amdgcn_mfma_f32_16x16x32_bf16(a1[i], bh1[j], acc[4 + i][2 + j], 0, 0, 0);
      }
    __builtin_amdgcn_s_setprio(0);
    __builtin_amdgcn_s_barrier();

    // ---- phase 3: no ds_reads (A-hi + held B-lo); stage B-g2,g3(t+2)->bu;
    //      counted gate: t+2's 6 loads may stay in flight.
    if (t + 2 < NT) { STAGE_B(t + 2, 2, bu); STAGE_B(t + 2, 3, bu); }
    __builtin_amdgcn_s_barrier();
    __builtin_amdgcn_s_setprio(1);
#pragma unroll
    for (int i = 0; i < 4; ++i)
#pragma unroll
      for (int j = 0; j < 2; ++j) {
        acc[4 + i][j] = __builtin_amdgcn_mfma_f32_16x16x32_bf16(a0[i], bl0[j], acc[4 + i][j], 0, 0, 0);
        acc[4 + i][j] = __builtin_amdgcn_mfma_f32_16x16x32_bf16(a1[i], bl1[j], acc[4 + i][j], 0, 0, 0);
      }
    __builtin_amdgcn_s_setprio(0);
    if (t + 2 < NT) {
      asm volatile("s_waitcnt vmcnt(6)" ::: "memory");
    } else if (t + 1 < NT) {
      asm volatile("s_waitcnt vmcnt(0)" ::: "memory");
    }
    __builtin_amdgcn_s_barrier();
  }
#undef STAGE_A
#undef STAGE_B

  // epilogue: C/D 16x16x32 layout: row = fq*4 + reg, col = fr
  const int er = m0 + wm + fq * 4;
  const int ec = n0 + wn + fr;
  float* const dst6 = (EPI == 6) ? (kh ? Cf2 : Cf) : nullptr;
#pragma unroll
  for (int qm = 0; qm < 2; ++qm) {
#pragma unroll
    for (int i = 0; i < 4; ++i) {
#pragma unroll
      for (int r = 0; r < 4; ++r) {
        const int gr = er + qm * 64 + i * 16 + r;
#pragma unroll
        for (int j = 0; j < 4; ++j) {
          const int gc = ec + j * 16;
          const size_t idx = (size_t)gr * ldc + gc;
          float v = acc[qm * 4 + i][j][r];
          if (EPI == 0) {
            Cb[idx] = (bf16)(v + bias[gc]);
          } else if (EPI == 1) {
            Cb[idx] = (bf16)(v + bias[gr]);
          } else if (EPI == 2) {
            Cb[idx] = (bf16)(v * scale);
          } else if (EPI == 4) {
            v += bias[gc];
            Cb[idx] = (bf16)(v > 0.f ? v : 0.f);
          } else {  // EPI == 6
            dst6[idx] = v;
          }
        }
      }
    }
  }
}

// ---------------------------------------------------------------------------
// combine: out = y0 + y1 [+ bias[col]] [+ addf] [+ (float)addb]; fused LN sums.
__global__ __launch_bounds__(256)
void combine_ln(const float* __restrict__ y0, const float* __restrict__ y1,
                const float* __restrict__ bias, const float* __restrict__ addf,
                const bf16* __restrict__ addb,
                float* __restrict__ out, float* __restrict__ red,
                int colMask, int total4)
{
  float ls = 0.f, ls2 = 0.f;
  for (int idx = blockIdx.x * 256 + threadIdx.x; idx < total4;
       idx += gridDim.x * 256) {
    const size_t i = (size_t)idx * 4;
    const float4 u0 = *(const float4*)(y0 + i);
    const float4 u1 = *(const float4*)(y1 + i);
    float vx = u0.x + u1.x, vy = u0.y + u1.y, vz = u0.z + u1.z, vw = u0.w + u1.w;
    if (bias) {
      const float4 b = *(const float4*)(bias + (int)(i & colMask));
      vx += b.x; vy += b.y; vz += b.z; vw += b.w;
    }
    if (addf) {
      const float4 a = *(const float4*)(addf + i);
      vx += a.x; vy += a.y; vz += a.z; vw += a.w;
    }
    if (addb) {
      const bf16x4 a = *(const bf16x4*)(addb + i);
      vx += (float)a[0]; vy += (float)a[1]; vz += (float)a[2]; vw += (float)a[3];
    }
    float4 o; o.x = vx; o.y = vy; o.z = vz; o.w = vw;
    *(float4*)(out + i) = o;
    ls  += vx + vy + vz + vw;
    ls2 += vx * vx + vy * vy + vz * vz + vw * vw;
  }
#pragma unroll
  for (int o = 32; o; o >>= 1) {
    ls  += __shfl_xor(ls,  o, 64);
    ls2 += __shfl_xor(ls2, o, 64);
  }
  __shared__ float sr[8];
  const int lane = threadIdx.x & 63, wave = threadIdx.x >> 6;
  if (lane == 0) { sr[wave * 2] = ls; sr[wave * 2 + 1] = ls2; }
  __syncthreads();
  if (threadIdx.x == 0) {
    atomicAdd(red,     sr[0] + sr[2] + sr[4] + sr[6]);
    atomicAdd(red + 1, sr[1] + sr[3] + sr[5] + sr[7]);
  }
}

// ---------------------------------------------------------------------------
__global__ __launch_bounds__(256)
void cvt_f32_bf16(const float* __restrict__ src, bf16* __restrict__ dst)
{
  const size_t i = ((size_t)blockIdx.x * 256 + threadIdx.x) * 4;
  const float4 t = *(const float4*)(src + i);
  bf16x4 b;
  b[0] = (bf16)t.x; b[1] = (bf16)t.y; b[2] = (bf16)t.z; b[3] = (bf16)t.w;
  *(bf16x4*)(dst + i) = b;
}

// fp32 [R,C] -> bf16 [C,R]
__global__ __launch_bounds__(256)
void transpose_cvt(const float* __restrict__ src, bf16* __restrict__ dst, int R, int C)
{
  __shared__ float tile[32][33];
  const int c0 = blockIdx.x * 32, r0 = blockIdx.y * 32;
  const int tx = threadIdx.x & 31, ty = threadIdx.x >> 5;
#pragma unroll
  for (int rr = ty; rr < 32; rr += 8)
    tile[rr][tx] = src[(size_t)(r0 + rr) * C + (c0 + tx)];
  __syncthreads();
#pragma unroll
  for (int rr = ty; rr < 32; rr += 8)
    dst[(size_t)(c0 + rr) * R + (r0 + tx)] = (bf16)tile[tx][rr];
}

__global__ __launch_bounds__(256)
void concat_bias(const float* __restrict__ a, const float* __restrict__ b,
                 float* __restrict__ o)
{
  const int i = blockIdx.x * 256 + threadIdx.x;   // grid 16 -> 4096
  o[i] = (i < 2048) ? a[i] : b[i - 2048];
}

// ---------------------------------------------------------------------------
__global__ __launch_bounds__(256)
void softmax_rows(bf16* __restrict__ P)
{
  const int row  = blockIdx.x;
  bf16* p = P + (size_t)row * 4096;
  const int tid  = threadIdx.x;
  const int lane = tid & 63, wave = tid >> 6;

  bf16x8 c0 = *(const bf16x8*)(p + tid * 16);
  bf16x8 c1 = *(const bf16x8*)(p + tid * 16 + 8);
  float v[16];
#pragma unroll
  for (int i = 0; i < 8; ++i) { v[i] = (float)c0[i]; v[8 + i] = (float)c1[i]; }

  float m = v[0];
#pragma unroll
  for (int i = 1; i < 16; ++i) m = fmaxf(m, v[i]);
#pragma unroll
  for (int o = 32; o; o >>= 1) m = fmaxf(m, __shfl_xor(m, o, 64));
  __shared__ float sred[8];
  if (lane == 0) sred[wave] = m;
  __syncthreads();
  m = fmaxf(fmaxf(sred[0], sred[1]), fmaxf(sred[2], sred[3]));

  float s = 0.f;
#pragma unroll
  for (int i = 0; i < 16; ++i) { v[i] = __expf(v[i] - m); s += v[i]; }
#pragma unroll
  for (int o = 32; o; o >>= 1) s += __shfl_xor(s, o, 64);
  if (lane == 0) sred[4 + wave] = s;
  __syncthreads();
  s = sred[4] + sred[5] + sred[6] + sred[7];

  const float inv = 1.f / s;
  bf16x8 o0, o1;
#pragma unroll
  for (int i = 0; i < 8; ++i) { o0[i] = (bf16)(v[i] * inv); o1[i] = (bf16)(v[8 + i] * inv); }
  *(bf16x8*)(p + tid * 16)     = o0;
  *(bf16x8*)(p + tid * 16 + 8) = o1;
}

// ---------------------------------------------------------------------------
__global__ void ln_finalize(float* red, float n)
{
  const float mu  = red[0] / n;
  const float var = red[1] / n - mu * mu;
  red[2] = mu;
  red[3] = rsqrtf(var + 1e-5f);
}

__global__ __launch_bounds__(256)
void ln_apply(const float* __restrict__ y, const float* __restrict__ red,
              float* __restrict__ of, bf16* __restrict__ ob)
{
  const float mu = red[2], rs = red[3];
  const size_t i = ((size_t)blockIdx.x * 256 + threadIdx.x) * 4;
  float4 t = *(const float4*)(y + i);
  t.x = (t.x - mu) * rs; t.y = (t.y - mu) * rs;
  t.z = (t.z - mu) * rs; t.w = (t.w - mu) * rs;
  if (of) *(float4*)(of + i) = t;
  if (ob) {
    bf16x4 b;
    b[0] = (bf16)t.x; b[1] = (bf16)t.y; b[2] = (bf16)t.z; b[3] = (bf16)t.w;
    *(bf16x4*)(ob + i) = b;
  }
}

// ---------------------------------------------------------------------------
extern "C" void kernel_launch(void* const* d_in, const int* in_sizes, int n_in,
                              void* d_out, int out_size, void* d_ws, size_t ws_size,
                              hipStream_t stream)
{
  const float* x  = (const float*)d_in[0];
  const float* Wq = (const float*)d_in[1];
  const float* bq = (const float*)d_in[2];
  const float* Wk = (const float*)d_in[3];
  const float* bk = (const float*)d_in[4];
  const float* Wv = (const float*)d_in[5];
  const float* bv = (const float*)d_in[6];
  const float* W1 = (const float*)d_in[7];
  const float* b1 = (const float*)d_in[8];
  const float* W2 = (const float*)d_in[9];
  const float* b2 = (const float*)d_in[10];
  float* out = (float*)d_out;

  const size_t MB = 1ull << 20;
  char* ws = (char*)d_ws;

  // Layout (peak 216 MB + 20 KB; 248 MB proven safe):
  //   0- 16: xb / hb (bf16)
  //  16- 32: WqkT [4096,2048] bf16  (rows 0-2047 Wq^T, 2048-4095 Wk^T)
  //  32- 40: WvT   40- 72: W1T   72-104: W2T
  // 104-136: QKb [S,4096] bf16 (Qb=base, Kb=base+2048); reused: y1_pv (f32),
  //          then act[0:32MB]
  // 136-168: Pb [S,S] bf16; reused as act[32:64MB]
  // 168-184: VbT
  // 184-216: y (f32)
  //  16- 48  reuse during FFN2: y1_f2 (f32, over dead WqkT/WvT/W1T-head)
  // 216+   : red (8 f), bqk (4096 f)
  bf16*  xb   = (bf16*)(ws);
  bf16*  hb   = xb;
  bf16*  WqkT = (bf16*)(ws + 16 * MB);
  bf16*  WvT  = (bf16*)(ws + 32 * MB);
  bf16*  W1T  = (bf16*)(ws + 40 * MB);
  bf16*  W2T  = (bf16*)(ws + 72 * MB);
  bf16*  QKb  = (bf16*)(ws + 104 * MB);
  float* y1pv = (float*)(ws + 104 * MB);
  bf16*  Pb   = (bf16*)(ws + 136 * MB);
  bf16*  act  = (bf16*)(ws + 104 * MB);
  bf16*  VbT  = (bf16*)(ws + 168 * MB);
  float* y    = (float*)(ws + 184 * MB);
  float* y1f2 = (float*)(ws + 16 * MB);
  float* red  = (float*)(ws + 216 * MB);
  float* bqk  = (float*)(ws + 216 * MB + 4096);

  hipMemsetAsync(red, 0, 32, stream);

  const dim3 blk(256);
  const dim3 blkg(512);
  const int nElemBlocks = (S * E) / 1024;
  const int total4 = (S * E) / 4;

  cvt_f32_bf16<<<dim3(nElemBlocks), blk, 0, stream>>>(x, xb);
  transpose_cvt<<<dim3(E / 32, E / 32), blk, 0, stream>>>(Wq, WqkT, E, E);
  transpose_cvt<<<dim3(E / 32, E / 32), blk, 0, stream>>>(Wk, WqkT + (size_t)E * E, E, E);
  transpose_cvt<<<dim3(E / 32, E / 32), blk, 0, stream>>>(Wv, WvT, E, E);
  transpose_cvt<<<dim3(H / 32, E / 32), blk, 0, stream>>>(W1, W1T, E, H);
  transpose_cvt<<<dim3(E / 32, H / 32), blk, 0, stream>>>(W2, W2T, H, E);
  concat_bias<<<dim3(16), blk, 0, stream>>>(bq, bk, bqk);

  // merged [Q|K] = x @ [Wq|Wk] + [bq|bk]  (256 WGs, full chip)
  gemm256<0, false><<<dim3(4096 / 256, S / 256), blkg, 0, stream>>>(
      xb, E, WqkT, E, QKb, nullptr, nullptr, 4096, bqk, S, 4096, E, 0.f);
  // V^T[E,S] = WvT @ x^T + bv[row]  (128 WGs)
  gemm256<1, false><<<dim3(S / 256, E / 256), blkg, 0, stream>>>(
      WvT, E, xb, E, VbT, nullptr, nullptr, S, bv, E, S, E, 0.f);

  // scores = (Q @ K^T)/64 -> bf16, softmax rows  (256 WGs)
  gemm256<2, false><<<dim3(S / 256, S / 256), blkg, 0, stream>>>(
      QKb, 4096, QKb + 2048, 4096, Pb, nullptr, nullptr, S, nullptr,
      S, S, E, 1.0f / 64.0f);
  softmax_rows<<<dim3(S), blk, 0, stream>>>(Pb);

  // P @ V split-K x2 -> partials (256 WGs full chip), combine + x + LN sums
  gemm256<6, true><<<dim3(E / 256, (S / 256) * 2), blkg, 0, stream>>>(
      Pb, S, VbT, S, nullptr, y, y1pv, E, nullptr, S, E, S, 0.f);
  combine_ln<<<dim3(2048), blk, 0, stream>>>(
      y, y1pv, nullptr, x, nullptr, y, red, E - 1, total4);
  ln_finalize<<<1, 1, 0, stream>>>(red, (float)((size_t)S * E));
  ln_apply<<<dim3(nElemBlocks), blk, 0, stream>>>(y, red, nullptr, hb);

  // act = relu(h @ W1 + b1)  (512 WGs)
  gemm256<4, false><<<dim3(H / 256, S / 256), blkg, 0, stream>>>(
      hb, E, W1T, E, act, nullptr, nullptr, H, b1, S, H, E, 0.f);

  // act @ W2 split-K x2 -> partials, combine + b2 + h + LN sums
  gemm256<6, true><<<dim3(E / 256, (S / 256) * 2), blkg, 0, stream>>>(
      act, H, W2T, H, nullptr, y, y1f2, E, nullptr, S, E, H, 0.f);
  combine_ln<<<dim3(2048), blk, 0, stream>>>(
      y, y1f2, b2, nullptr, hb, y, red + 4, E - 1, total4);
  ln_finalize<<<1, 1, 0, stream>>>(red + 4, (float)((size_t)S * E));
  ln_apply<<<dim3(nElemBlocks), blk, 0, stream>>>(y, red + 4, out, nullptr);
}